// Round 7
// baseline (576.957 us; speedup 1.0000x reference)
//
#include <hip/hip_runtime.h>
#include <hip/hip_bf16.h>
#include <math.h>

#define BB     2
#define SS     2048
#define HH     768
#define NHEAD  12
#define DHEAD  64
#define FFD    3072
#define NLAYER 2
#define MTOK   (BB*SS)   // 4096 rows
#define LOG2E  1.4426950408889634f
#define QSCALE 0.18033688011112042f   // 0.125 * log2(e)

typedef __attribute__((ext_vector_type(8))) short bf16x8;
typedef __attribute__((ext_vector_type(4))) short bf16x4;
typedef __attribute__((ext_vector_type(4))) float f32x4;

__device__ __forceinline__ short f2bs(float f) {
    union { float f; unsigned u; } v; v.f = f;
    unsigned r = v.u + 0x7FFF + ((v.u >> 16) & 1);   // RNE to bf16
    return (short)(r >> 16);
}
__device__ __forceinline__ float bs2f(short s) {
    union { unsigned u; float f; } v; v.u = ((unsigned)(unsigned short)s) << 16;
    return v.f;
}
// single-instruction 2^x (exp2f lowers to the slow precise OCML path; v_exp_f32 IS 2^x)
__device__ __forceinline__ float fexp2(float x) {
    float r; asm("v_exp_f32 %0, %1" : "=v"(r) : "v"(x)); return r;
}
// async 16B/lane global->LDS (lds dst = wave-uniform base + lane*16)
__device__ __forceinline__ void gl2lds16(const short* g, short* l) {
    __builtin_amdgcn_global_load_lds(
        (const __attribute__((address_space(1))) unsigned int*)g,
        (__attribute__((address_space(3))) unsigned int*)l, 16, 0, 0);
}

// ---------------------------------------------------------------------------
// Prep: batched transpose+cvt. Wt[n*K+k] = bf16(W[k*N+n]).
// ---------------------------------------------------------------------------
struct TJobs { const float* src[8]; short* dst[8]; };

__global__ __launch_bounds__(256)
void transpose_cvt_batch(TJobs jobs, int K, int N)
{
    const float* __restrict__ W  = jobs.src[blockIdx.z];
    short* __restrict__ Wt = jobs.dst[blockIdx.z];
    __shared__ short tile[32][33];
    const int k0 = blockIdx.x * 32, n0 = blockIdx.y * 32;
    const int tx = threadIdx.x & 31, ty = threadIdx.x >> 5;
#pragma unroll
    for (int i = 0; i < 4; i++)
        tile[ty + i*8][tx] = f2bs(W[(size_t)(k0 + ty + i*8) * N + n0 + tx]);
    __syncthreads();
#pragma unroll
    for (int i = 0; i < 4; i++)
        Wt[(size_t)(n0 + ty + i*8) * K + k0 + tx] = tile[tx][ty + i*8];
}

// Prep: dst = bf16(src)
__global__ __launch_bounds__(256)
void cvt_bf16(const float* __restrict__ src, short* __restrict__ dst, int n)
{
    const int i = blockIdx.x * 256 + threadIdx.x;
    if (i < n) dst[i] = f2bs(src[i]);
}

// Prep: bqkv[l*2304 + {0|768|1536} + c] = {bq|bk|bv}[l*768 + c]
__global__ __launch_bounds__(256)
void pack_bias(const float* __restrict__ bq, const float* __restrict__ bk,
               const float* __restrict__ bv, float* __restrict__ bqkv)
{
    const int t = blockIdx.x * 256 + threadIdx.x;
    if (t >= NLAYER * 2304) return;
    const int l = t / 2304, r = t % 2304;
    const float* src = (r < 768) ? bq : (r < 1536 ? bk : bv);
    bqkv[t] = src[l*768 + (r % 768)];
}

// ---------------------------------------------------------------------------
// Prep: bias+mask in SWAPPED (S^T) MFMA C-fragment order, LOG2-DOMAIN:
// value = (bias*coef + (1-mask)*(-10000)) * log2(e)   [pairs with Q*0.125*log2e]
// ---------------------------------------------------------------------------
__global__ __launch_bounds__(256)
void bias_frag_prep(const float* __restrict__ biasM, const float* __restrict__ mask,
                    const float* __restrict__ coefp, short* __restrict__ bFrag)
{
    __shared__ float tile[64][129];   // 33 KB
    const int tid = threadIdx.x;
    const int qb = blockIdx.x, q0 = qb*64, k0 = blockIdx.y*128;
#pragma unroll
    for (int p = 0; p < 8; p++) {
        const int row = p*8 + (tid >> 5);
        const int col = (tid & 31) * 4;
        float4 v = *(const float4*)&biasM[(size_t)(q0 + row)*SS + k0 + col];
        tile[row][col+0] = v.x; tile[row][col+1] = v.y;
        tile[row][col+2] = v.z; tile[row][col+3] = v.w;
    }
    __syncthreads();
    const float coef = coefp[0];
    const int lane = tid & 63, w = tid >> 6;
    const int l16 = lane & 15, g = lane >> 4;
    const int qrow = w*16 + l16;
#pragma unroll
    for (int b = 0; b < BB; b++) {
#pragma unroll
        for (int kt = 0; kt < 8; kt++) {
            bf16x4 o;
#pragma unroll
            for (int r = 0; r < 4; r++) {
                const int kk = kt*16 + g*4 + r;
                const float madd = (1.f - mask[b*SS + k0 + kk]) * (-10000.0f);
                o[r] = f2bs((tile[qrow][kk] * coef + madd) * LOG2E);
            }
            const size_t idx = ((((size_t)b*32 + qb)*4 + w)*128 + (k0>>4) + kt)*256 + lane*4;
            *(bf16x4*)&bFrag[idx] = o;
        }
    }
}

// ---------------------------------------------------------------------------
// C[M,N](bf16) = act(A[M,K](bf16) @ Bt[N,K](bf16)^T + bias[N](f32))
// 128x128 tile, 4 waves, 16x16x32 MFMA, global_load_lds, BK=64 dual-buffer.
// Cols >= vsplit are written TRANSPOSED to VtOut[col-vsplit][row] (short4).
// Cols <  qcols get *qscale after bias (Q pre-scaling for log2-softmax).
// ---------------------------------------------------------------------------
__global__ __launch_bounds__(256)
void gemm_mfma(const short* __restrict__ A, const short* __restrict__ Bt,
               const float* __restrict__ bias, short* __restrict__ C, int ldc,
               int M, int N, int K, int gelu, short* __restrict__ VtOut, int vsplit,
               float qscale, int qcols)
{
    __shared__ short sA[2][128*32];   // 32 KB total
    __shared__ short sB[2][128*32];
    const int tid  = threadIdx.x;
    const int w    = tid >> 6;
    const int lane = tid & 63;
    const int l16  = lane & 15, g = lane >> 4;
    const int wm   = w & 1, wn = w >> 1;
    const size_t m0 = (size_t)blockIdx.y * 128, n0 = (size_t)blockIdx.x * 128;

    const int srow = lane >> 2;
    const int kc   = lane & 3;

    f32x4 acc[4][4];
#pragma unroll
    for (int i = 0; i < 4; i++)
#pragma unroll
        for (int j = 0; j < 4; j++) acc[i][j] = (f32x4){0.f,0.f,0.f,0.f};

    const short* gA0 = A  + (m0 + w*32 +      srow) * (size_t)K + kc*8;
    const short* gA1 = A  + (m0 + w*32 + 16 + srow) * (size_t)K + kc*8;
    const short* gB0 = Bt + (n0 + w*32 +      srow) * (size_t)K + kc*8;
    const short* gB1 = Bt + (n0 + w*32 + 16 + srow) * (size_t)K + kc*8;
    const int oA0 = (w*32     )*32, oA1 = (w*32 + 16)*32;

    for (int k0 = 0; k0 < K; k0 += 64) {
        gl2lds16(gA0 + k0,      &sA[0][oA0]);
        gl2lds16(gA1 + k0,      &sA[0][oA1]);
        gl2lds16(gB0 + k0,      &sB[0][oA0]);
        gl2lds16(gB1 + k0,      &sB[0][oA1]);
        gl2lds16(gA0 + k0 + 32, &sA[1][oA0]);
        gl2lds16(gA1 + k0 + 32, &sA[1][oA1]);
        gl2lds16(gB0 + k0 + 32, &sB[1][oA0]);
        gl2lds16(gB1 + k0 + 32, &sB[1][oA1]);
        __syncthreads();

#pragma unroll
        for (int s = 0; s < 2; s++) {
            bf16x8 af[4], bfr[4];
#pragma unroll
            for (int mt = 0; mt < 4; mt++)
                af[mt] = *(const bf16x8*)&sA[s][(wm*64 + mt*16 + l16)*32 + g*8];
#pragma unroll
            for (int nt = 0; nt < 4; nt++)
                bfr[nt] = *(const bf16x8*)&sB[s][(wn*64 + nt*16 + l16)*32 + g*8];
#pragma unroll
            for (int mt = 0; mt < 4; mt++)
#pragma unroll
                for (int nt = 0; nt < 4; nt++)
                    acc[mt][nt] = __builtin_amdgcn_mfma_f32_16x16x32_bf16(
                                      af[mt], bfr[nt], acc[mt][nt], 0, 0, 0);
        }
        __syncthreads();
    }

#pragma unroll
    for (int mt = 0; mt < 4; mt++) {
        const size_t row0 = m0 + wm*64 + mt*16 + g*4;
#pragma unroll
        for (int nt = 0; nt < 4; nt++) {
            const size_t col = n0 + wn*64 + nt*16 + l16;
            if ((int)col >= vsplit) {           // V part -> transposed bf16 out
                short4 t;
                t.x = f2bs(acc[mt][nt][0] + bias[col]);
                t.y = f2bs(acc[mt][nt][1] + bias[col]);
                t.z = f2bs(acc[mt][nt][2] + bias[col]);
                t.w = f2bs(acc[mt][nt][3] + bias[col]);
                *(short4*)&VtOut[(size_t)(col - vsplit)*MTOK + row0] = t;
            } else {
#pragma unroll
                for (int r = 0; r < 4; r++) {
                    float v = acc[mt][nt][r] + bias[col];
                    if ((int)col < qcols) v *= qscale;
                    if (gelu) v = 0.5f * v * (1.f + erff(v * 0.70710678118f));
                    C[(row0 + r) * (size_t)ldc + col] = f2bs(v);
                }
            }
        }
    }
}

// ---------------------------------------------------------------------------
// SPLIT-K=2 variant for the N=768 GEMMs (AO: K=768, FFN2: K=3072).
// grid (N/64, M/128, 2) = 768 blocks = 3/CU (was 384 = 1.5/CU).
// Writes f32 PARTIALS (no bias) to P[z][row][col]; add_ln3 fuses the sum.
// ---------------------------------------------------------------------------
__global__ __launch_bounds__(256)
void gemm_n64_splitk(const short* __restrict__ A, const short* __restrict__ Bt,
                     float* __restrict__ P, int K)
{
    const int K2 = K >> 1;
    const int z  = blockIdx.z;
    __shared__ short sA[2][128*32];   // 32 KB
    __shared__ short sB[2][64*32];    // 16 KB
    const int tid  = threadIdx.x;
    const int w    = tid >> 6;
    const int lane = tid & 63;
    const int l16  = lane & 15, g = lane >> 4;
    const int wm   = w & 1, wn = w >> 1;
    const size_t m0 = (size_t)blockIdx.y * 128, n0 = (size_t)blockIdx.x * 64;

    const int srow = lane >> 2;
    const int kc   = lane & 3;

    f32x4 acc[4][2];
#pragma unroll
    for (int i = 0; i < 4; i++)
#pragma unroll
        for (int j = 0; j < 2; j++) acc[i][j] = (f32x4){0.f,0.f,0.f,0.f};

    const short* gA0 = A  + (m0 + w*32 +      srow) * (size_t)K + z*K2 + kc*8;
    const short* gA1 = A  + (m0 + w*32 + 16 + srow) * (size_t)K + z*K2 + kc*8;
    const short* gB0 = Bt + (n0 + w*16 +      srow) * (size_t)K + z*K2 + kc*8;
    const int oA0 = (w*32     )*32, oA1 = (w*32 + 16)*32, oB0 = (w*16)*32;

    for (int k0 = 0; k0 < K2; k0 += 64) {
        gl2lds16(gA0 + k0,      &sA[0][oA0]);
        gl2lds16(gA1 + k0,      &sA[0][oA1]);
        gl2lds16(gB0 + k0,      &sB[0][oB0]);
        gl2lds16(gA0 + k0 + 32, &sA[1][oA0]);
        gl2lds16(gA1 + k0 + 32, &sA[1][oA1]);
        gl2lds16(gB0 + k0 + 32, &sB[1][oB0]);
        __syncthreads();

#pragma unroll
        for (int s = 0; s < 2; s++) {
            bf16x8 af[4], bfr[2];
#pragma unroll
            for (int mt = 0; mt < 4; mt++)
                af[mt] = *(const bf16x8*)&sA[s][(wm*64 + mt*16 + l16)*32 + g*8];
#pragma unroll
            for (int nt = 0; nt < 2; nt++)
                bfr[nt] = *(const bf16x8*)&sB[s][(wn*32 + nt*16 + l16)*32 + g*8];
#pragma unroll
            for (int mt = 0; mt < 4; mt++)
#pragma unroll
                for (int nt = 0; nt < 2; nt++)
                    acc[mt][nt] = __builtin_amdgcn_mfma_f32_16x16x32_bf16(
                                      af[mt], bfr[nt], acc[mt][nt], 0, 0, 0);
        }
        __syncthreads();
    }

    float* Pz = P + (size_t)z * MTOK * HH;
#pragma unroll
    for (int mt = 0; mt < 4; mt++) {
        const size_t row0 = m0 + wm*64 + mt*16 + g*4;
#pragma unroll
        for (int nt = 0; nt < 2; nt++) {
            const size_t col = n0 + wn*32 + nt*16 + l16;
#pragma unroll
            for (int r = 0; r < 4; r++)
                Pz[(row0 + r) * (size_t)HH + col] = acc[mt][nt][r];
        }
    }
}

// ---------------------------------------------------------------------------
// Flash attention, KV-SPLIT x2 (flash-decode): grid (32, 12, BB*2); block z
// handles batch z>>1, keys [half*1024, half*1024+1024). Writes UN-NORMALIZED
// O (f32) to PO[half] and per-row (m,l) to ML; add_merge combines exactly.
// 1536 blocks -> 4 resident blocks/CU (16 waves, was 12). R6 core unchanged:
// swapped QK^T, log2-domain fexp2 softmax, in-register P frags, LDS-staged
// K/V with next-tile register prefetch. + defer-max (bit-exact skip of
// O-rescale when no q-row's max grew: alpha==1 identically).
// ---------------------------------------------------------------------------
__global__ __launch_bounds__(256, 4)
void attn_fused(const short* __restrict__ QK, const short* __restrict__ Vt,
                const short* __restrict__ bFrag, float* __restrict__ PO,
                float2* __restrict__ ML)
{
    __shared__ short sK[128*72];    // 18.4 KB  [key][dim]
    __shared__ short sV[64*136];    // 17.4 KB  [dim][key]

    const int qb   = blockIdx.x;
    const int q0   = qb * 64;
    const int h    = blockIdx.y;
    const int b    = blockIdx.z >> 1;
    const int half = blockIdx.z & 1;
    const int koff = half * (SS/2);
    const int tid  = threadIdx.x;
    const int w    = tid >> 6;
    const int lane = tid & 63;
    const int l16  = lane & 15;
    const int g    = lane >> 4;

    // Q B-frags (held all kernel; already scaled by 0.125*log2e)
    const short* qrow = QK + ((size_t)(b*SS) + q0 + w*16 + l16) * 1536 + h*64;
    bf16x8 bQ0 = *(const bf16x8*)(qrow + g*8);
    bf16x8 bQ1 = *(const bf16x8*)(qrow + 32 + g*8);

    f32x4 O[4];
#pragma unroll
    for (int d = 0; d < 4; d++) O[d] = (f32x4){0.f,0.f,0.f,0.f};
    float m_q = -1e30f, l_q = 0.f;   // per-lane online-softmax state, q = l16

    // staging maps: consecutive lanes cover one contiguous row
    const int krow = tid >> 3, kch = tid & 7;     // K: 32 rows x 8 chunks /pass
    const int vrow = tid >> 4, vch = tid & 15;    // V: 16 rows x 16 chunks /pass
    const short* Kg = QK + ((size_t)(b*SS) + koff + krow)*1536 + 768 + h*64 + kch*8;
    const short* Vg = Vt + ((size_t)(h*64 + vrow))*MTOK + b*SS + koff + vch*8;
    // bias frags: per wave, per k-subtile: one coalesced bf16x4 at lane*4
    const short* bF = bFrag + ((((size_t)b*32 + qb)*4 + w)*128)*256 + lane*4;

    // prologue prefetch (tile 0 of this half)
    bf16x8 kreg[4], vreg[4];
#pragma unroll
    for (int p = 0; p < 4; p++) {
        kreg[p] = *(const bf16x8*)(Kg + (size_t)(p*32)*1536);
        vreg[p] = *(const bf16x8*)(Vg + (size_t)(p*16)*MTOK);
    }

    for (int k0 = 0; k0 < SS/2; k0 += 128) {
        // ---- bias frags for this tile (independent of LDS) ----
        const short* bFt = bF + ((size_t)((koff + k0) >> 4))*256;
        bf16x4 bb[8];
#pragma unroll
        for (int t = 0; t < 8; t++)
            bb[t] = *(const bf16x4*)(bFt + (size_t)t*256);

        // ---- staged regs -> LDS ----
#pragma unroll
        for (int p = 0; p < 4; p++) {
            *(bf16x8*)&sK[(p*32 + krow)*72 + kch*8]   = kreg[p];
            *(bf16x8*)&sV[(p*16 + vrow)*136 + vch*8]  = vreg[p];
        }
        __syncthreads();

        // ---- prefetch next tile (overlaps with compute below) ----
        if (k0 + 128 < SS/2) {
#pragma unroll
            for (int p = 0; p < 4; p++) {
                kreg[p] = *(const bf16x8*)(Kg + (size_t)(k0 + 128 + p*32)*1536);
                vreg[p] = *(const bf16x8*)(Vg + (size_t)(p*16)*MTOK + k0 + 128);
            }
        }

        // ---- S^T = K Q'^T + bias frag (log2-domain) ----
        float S[8][4];
#pragma unroll
        for (int t = 0; t < 8; t++) {
            bf16x8 aK0 = *(const bf16x8*)&sK[(t*16 + l16)*72 + g*8];
            bf16x8 aK1 = *(const bf16x8*)&sK[(t*16 + l16)*72 + 32 + g*8];
            f32x4 c = (f32x4){0.f,0.f,0.f,0.f};
            c = __builtin_amdgcn_mfma_f32_16x16x32_bf16(aK0, bQ0, c, 0, 0, 0);
            c = __builtin_amdgcn_mfma_f32_16x16x32_bf16(aK1, bQ1, c, 0, 0, 0);
#pragma unroll
            for (int r = 0; r < 4; r++)
                S[t][r] = c[r] + bs2f(bb[t][r]);
        }

        // ---- online softmax (base-2): per-lane trees + 2 shuffles ----
        float tm[8];
#pragma unroll
        for (int t = 0; t < 8; t++)
            tm[t] = fmaxf(fmaxf(S[t][0], S[t][1]), fmaxf(S[t][2], S[t][3]));
        float mx = fmaxf(fmaxf(fmaxf(tm[0], tm[1]), fmaxf(tm[2], tm[3])),
                         fmaxf(fmaxf(tm[4], tm[5]), fmaxf(tm[6], tm[7])));
        mx = fmaxf(mx, __shfl_xor(mx, 16));
        mx = fmaxf(mx, __shfl_xor(mx, 32));

        // defer-max: if NO q-row in this wave grew, alpha==1 exactly -> skip
        const bool grow = !__all(mx <= m_q);
        const float mnew = grow ? fmaxf(m_q, mx) : m_q;

        float ts[8];
#pragma unroll
        for (int t = 0; t < 8; t++) {
            float p0 = fexp2(S[t][0] - mnew);
            float p1 = fexp2(S[t][1] - mnew);
            float p2 = fexp2(S[t][2] - mnew);
            float p3 = fexp2(S[t][3] - mnew);
            S[t][0] = p0; S[t][1] = p1; S[t][2] = p2; S[t][3] = p3;
            ts[t] = (p0 + p1) + (p2 + p3);
        }
        float rs = ((ts[0] + ts[1]) + (ts[2] + ts[3]))
                 + ((ts[4] + ts[5]) + (ts[6] + ts[7]));
        rs += __shfl_xor(rs, 16);
        rs += __shfl_xor(rs, 32);

        if (grow) {
            const float alpha = fexp2(m_q - mnew);
            l_q = l_q * alpha + rs;
            m_q = mnew;
            // rescale O (O rows live at q = g*4+r; alpha lives at q = l16)
#pragma unroll
            for (int r = 0; r < 4; r++) {
                const float ar = __shfl(alpha, g*4 + r);
#pragma unroll
                for (int d = 0; d < 4; d++) O[d][r] *= ar;
            }
        } else {
            l_q += rs;
        }

        // ---- PV: in-register P frags x sV B-frags ----
#define PVU(u)                                                                 \
        {                                                                      \
            unsigned pa, pb, pc, pe;                                           \
            asm("v_cvt_pk_bf16_f32 %0, %1, %2" : "=v"(pa)                      \
                : "v"(S[2*(u)][0]),   "v"(S[2*(u)][1]));                       \
            asm("v_cvt_pk_bf16_f32 %0, %1, %2" : "=v"(pb)                      \
                : "v"(S[2*(u)][2]),   "v"(S[2*(u)][3]));                       \
            asm("v_cvt_pk_bf16_f32 %0, %1, %2" : "=v"(pc)                      \
                : "v"(S[2*(u)+1][0]), "v"(S[2*(u)+1][1]));                     \
            asm("v_cvt_pk_bf16_f32 %0, %1, %2" : "=v"(pe)                      \
                : "v"(S[2*(u)+1][2]), "v"(S[2*(u)+1][3]));                     \
            asm("v_permlane32_swap_b32 %0, %1" : "+v"(pa), "+v"(pc));          \
            asm("v_permlane16_swap_b32 %0, %1" : "+v"(pa), "+v"(pc));          \
            asm("v_permlane32_swap_b32 %0, %1" : "+v"(pb), "+v"(pe));          \
            asm("v_permlane16_swap_b32 %0, %1" : "+v"(pb), "+v"(pe));          \
            union { unsigned uw[4]; bf16x8 v; } P_;                            \
            P_.uw[0] = pa; P_.uw[1] = pb; P_.uw[2] = pc; P_.uw[3] = pe;        \
            _Pragma("unroll")                                                  \
            for (int d = 0; d < 4; d++) {                                      \
                bf16x8 vv = *(const bf16x8*)&sV[(d*16 + l16)*136 + (u)*32 + g*8]; \
                O[d] = __builtin_amdgcn_mfma_f32_16x16x32_bf16(                \
                           P_.v, vv, O[d], 0, 0, 0);                           \
            }                                                                  \
        }
        PVU(0)
        PVU(1)
        PVU(2)
        PVU(3)
#undef PVU

        __syncthreads();   // before next tile restages sK/sV
    }

    // ---- epilogue: un-normalized O (f32) + per-row (m,l) ----
    float* PO_ = PO + (size_t)half * MTOK * HH;
#pragma unroll
    for (int d = 0; d < 4; d++)
#pragma unroll
        for (int r = 0; r < 4; r++)
            PO_[((size_t)(b*SS) + q0 + w*16 + g*4 + r)*HH + h*64 + d*16 + l16]
                = O[d][r];
    if (g == 0) {
        float2 ml; ml.x = m_q; ml.y = l_q;
        ML[((size_t)half*MTOK + b*SS + q0 + w*16 + l16)*NHEAD + h] = ml;
    }
}

// ---------------------------------------------------------------------------
// Flash-combine of the two KV halves: CTX = (P0*w0 + P1*w1)/(l0*w0 + l1*w1),
// w_i = 2^(m_i - max(m0,m1)). One WAVE per row.
// ---------------------------------------------------------------------------
__global__ __launch_bounds__(256)
void add_merge(const float* __restrict__ PO, const float2* __restrict__ ML,
               short* __restrict__ CTX)
{
    const int lane = threadIdx.x & 63;
    const int row  = blockIdx.x * 4 + (threadIdx.x >> 6);
    const size_t base = (size_t)row * HH;
    const size_t sH = (size_t)MTOK * HH;

#pragma unroll
    for (int p = 0; p < 3; p++) {
        const int c = p*256 + lane*4;
        const int h = c >> 6;
        float2 a = ML[(size_t)row*NHEAD + h];
        float2 bm = ML[(size_t)MTOK*NHEAD + (size_t)row*NHEAD + h];
        const float M  = fmaxf(a.x, bm.x);
        const float w0 = fexp2(a.x - M);
        const float w1 = fexp2(bm.x - M);
        const float linv = 1.f / (a.y*w0 + bm.y*w1);
        float4 p0 = *(const float4*)&PO[base + c];
        float4 p1 = *(const float4*)&PO[sH + base + c];
        bf16x4 ov;
        ov[0] = f2bs((p0.x*w0 + p1.x*w1) * linv);
        ov[1] = f2bs((p0.y*w0 + p1.y*w1) * linv);
        ov[2] = f2bs((p0.z*w0 + p1.z*w1) * linv);
        ov[3] = f2bs((p0.w*w0 + p1.w*w1) * linv);
        *(bf16x4*)&CTX[base + c] = ov;
    }
}

// ---------------------------------------------------------------------------
// Out(bf16) = LayerNorm(P0 + P1 + bias + R) * g + beta; optional fp32 OutF.
// P = two f32 split-K partials [2][MTOK][HH]; R = bf16 residual.
// One WAVE per row, shfl-only reductions.
// ---------------------------------------------------------------------------
__global__ __launch_bounds__(256)
void add_ln3(const float* __restrict__ P, const float* __restrict__ bvec,
             const short* __restrict__ R,
             const float* __restrict__ g, const float* __restrict__ beta,
             short* __restrict__ Out, float* __restrict__ OutF)
{
    const int lane = threadIdx.x & 63;
    const int row  = blockIdx.x * 4 + (threadIdx.x >> 6);
    const size_t base = (size_t)row * HH;
    const size_t sH = (size_t)MTOK * HH;

    float v[12];
    float s = 0.f;
#pragma unroll
    for (int p = 0; p < 3; p++) {
        const int c = p*256 + lane*4;
        float4 p0 = *(const float4*)&P[base + c];
        float4 p1 = *(const float4*)&P[sH + base + c];
        float4 bv4 = *(const float4*)&bvec[c];
        bf16x4 rv = *(const bf16x4*)&R[base + c];
        float x0 = p0.x + p1.x + bv4.x + bs2f(rv[0]);
        float x1 = p0.y + p1.y + bv4.y + bs2f(rv[1]);
        float x2 = p0.z + p1.z + bv4.z + bs2f(rv[2]);
        float x3 = p0.w + p1.w + bv4.w + bs2f(rv[3]);
        v[p*4+0] = x0; v[p*4+1] = x1; v[p*4+2] = x2; v[p*4+3] = x3;
        s += (x0 + x1) + (x2 + x3);
    }
    s += __shfl_xor(s, 1);  s += __shfl_xor(s, 2);  s += __shfl_xor(s, 4);
    s += __shfl_xor(s, 8);  s += __shfl_xor(s, 16); s += __shfl_xor(s, 32);
    const float mu = s * (1.f / HH);

    float s2 = 0.f;
#pragma unroll
    for (int j = 0; j < 12; j++) { float d = v[j] - mu; s2 += d * d; }
    s2 += __shfl_xor(s2, 1);  s2 += __shfl_xor(s2, 2);  s2 += __shfl_xor(s2, 4);
    s2 += __shfl_xor(s2, 8);  s2 += __shfl_xor(s2, 16); s2 += __shfl_xor(s2, 32);
    const float rstd = rsqrtf(s2 * (1.f / HH) + 1e-12f);

#pragma unroll
    for (int p = 0; p < 3; p++) {
        const int c = p*256 + lane*4;
        float4 gv = *(const float4*)&g[c];
        float4 bv = *(const float4*)&beta[c];
        float o0 = (v[p*4+0] - mu) * rstd * gv.x + bv.x;
        float o1 = (v[p*4+1] - mu) * rstd * gv.y + bv.y;
        float o2 = (v[p*4+2] - mu) * rstd * gv.z + bv.z;
        float o3 = (v[p*4+3] - mu) * rstd * gv.w + bv.w;
        bf16x4 ov; ov[0] = f2bs(o0); ov[1] = f2bs(o1); ov[2] = f2bs(o2); ov[3] = f2bs(o3);
        *(bf16x4*)&Out[base + c] = ov;
        if (OutF) {
            float4 of; of.x = o0; of.y = o1; of.z = o2; of.w = o3;
            *(float4*)&OutF[base + c] = of;
        }
    }
}

// ---------------------------------------------------------------------------
extern "C" void kernel_launch(void* const* d_in, const int* in_sizes, int n_in,
                              void* d_out, int out_size, void* d_ws, size_t ws_size,
                              hipStream_t stream)
{
    const float* hs    = (const float*)d_in[0];
    const float* mask  = (const float*)d_in[1];
    const float* biasM = (const float*)d_in[2];
    const float* coef  = (const float*)d_in[3];
    const float* Wq    = (const float*)d_in[4];
    const float* bq    = (const float*)d_in[5];
    const float* Wk    = (const float*)d_in[6];
    const float* bk    = (const float*)d_in[7];
    const float* Wv    = (const float*)d_in[8];
    const float* bv    = (const float*)d_in[9];
    const float* Wo    = (const float*)d_in[10];
    const float* bo    = (const float*)d_in[11];
    const float* ln1g  = (const float*)d_in[12];
    const float* ln1b  = (const float*)d_in[13];
    const float* Wi    = (const float*)d_in[14];
    const float* bi    = (const float*)d_in[15];
    const float* Wo2   = (const float*)d_in[16];
    const float* bo2   = (const float*)d_in[17];
    const float* ln2g  = (const float*)d_in[18];
    const float* ln2b  = (const float*)d_in[19];

    // ---- workspace (~109 MB; 138 MB proven available) ----
    const size_t sH   = (size_t)MTOK * HH;
    const size_t sQK  = (size_t)MTOK * 1536;
    const size_t sVt  = (size_t)HH * MTOK;
    const size_t WPL  = 7077888;
    short* wt    = (short*)d_ws;
    float* bqkv  = (float*)(wt + 2*WPL);
    short* bFrag = (short*)(bqkv + 2*2304);       // [2*SS*SS] bias+mask C-frags
    short* X     = bFrag + (size_t)2*SS*SS;
    short* X2    = X  + sH;
    short* QK    = X2 + sH;
    short* Vt    = QK + sQK;
    short* CTX   = Vt + sVt;
    float* PK    = (float*)(CTX + sH);            // [2][MTOK][HH] f32 partials
    float2* ML   = (float2*)(PK + 2*sH);          // [2][MTOK][NHEAD] (m,l)
    short* INTER = QK;

    const dim3 blk(256);

    // ---- prep: batched transposes, bias frags, bias pack, hs cvt ----
    TJobs jH, jI, jO;
    for (int l = 0; l < NLAYER; l++) {
        short* wl = wt + (size_t)l * WPL;
        jH.src[l*4+0] = Wq + (size_t)l*HH*HH;  jH.dst[l*4+0] = wl;
        jH.src[l*4+1] = Wk + (size_t)l*HH*HH;  jH.dst[l*4+1] = wl + 768*768;
        jH.src[l*4+2] = Wv + (size_t)l*HH*HH;  jH.dst[l*4+2] = wl + 1536*768;
        jH.src[l*4+3] = Wo + (size_t)l*HH*HH;  jH.dst[l*4+3] = wl + 1769472;
        jI.src[l] = Wi  + (size_t)l*HH*FFD;    jI.dst[l] = wl + 2359296;
        jO.src[l] = Wo2 + (size_t)l*FFD*HH;    jO.dst[l] = wl + 4718592;
    }
    transpose_cvt_batch<<<dim3(24,24,8), blk, 0, stream>>>(jH, HH, HH);
    transpose_cvt_batch<<<dim3(24,96,2), blk, 0, stream>>>(jI, HH, FFD);
    transpose_cvt_batch<<<dim3(96,24,2), blk, 0, stream>>>(jO, FFD, HH);
    bias_frag_prep<<<dim3(SS/64, SS/128), blk, 0, stream>>>(biasM, mask, coef, bFrag);
    pack_bias<<<dim3((NLAYER*2304 + 255)/256), blk, 0, stream>>>(bq, bk, bv, bqkv);
    cvt_bf16<<<dim3((int)((sH + 255)/256)), blk, 0, stream>>>(hs, X, (int)sH);

    const dim3 gQKV(2304/128, MTOK/128);      // [18, 32]
    const dim3 gSK (HH/64,    MTOK/128, 2);   // [12, 32, 2] split-K
    const dim3 gFF (FFD/128,  MTOK/128);      // [24, 32]
    const dim3 gA  (SS/64, NHEAD, BB*2);      // [32, 12, 4] = 1536 blocks (KV-split)
    const dim3 gLN (MTOK/4);                  // wave-per-row LN / merge
    const int NOSPLIT = 1 << 30;

    for (int l = 0; l < NLAYER; l++) {
        short* wl = wt + (size_t)l * WPL;
        gemm_mfma<<<gQKV, blk, 0, stream>>>(X, wl, bqkv + l*2304, QK, 1536,
                                            MTOK, 2304, HH, 0, Vt, 1536,
                                            QSCALE, 768);
        attn_fused<<<gA, blk, 0, stream>>>(QK, Vt, bFrag, PK, ML);
        add_merge<<<gLN, blk, 0, stream>>>(PK, ML, CTX);
        gemm_n64_splitk<<<gSK, blk, 0, stream>>>(CTX, wl + 1769472, PK, HH);
        add_ln3<<<gLN, blk, 0, stream>>>(PK, bo + l*HH, X, ln1g + l*HH, ln1b + l*HH,
                                         X2, nullptr);
        gemm_mfma<<<gFF, blk, 0, stream>>>(X2, wl + 2359296, bi + l*FFD, INTER, FFD,
                                           MTOK, FFD, HH, 1, nullptr, NOSPLIT,
                                           1.f, 0);
        gemm_n64_splitk<<<gSK, blk, 0, stream>>>(INTER, wl + 4718592, PK, FFD);
        add_ln3<<<gLN, blk, 0, stream>>>(PK, bo2 + l*HH, X2, ln2g + l*HH, ln2b + l*HH,
                                         X, (l == NLAYER-1) ? (float*)d_out : nullptr);
    }
}

// Round 8
// 539.632 us; speedup vs baseline: 1.0692x; 1.0692x over previous
//
#include <hip/hip_runtime.h>
#include <hip/hip_bf16.h>
#include <math.h>

#define BB     2
#define SS     2048
#define HH     768
#define NHEAD  12
#define DHEAD  64
#define FFD    3072
#define NLAYER 2
#define MTOK   (BB*SS)   // 4096 rows
#define LOG2E  1.4426950408889634f
#define QSCALE 0.18033688011112042f   // 0.125 * log2(e)

typedef __attribute__((ext_vector_type(8))) short bf16x8;
typedef __attribute__((ext_vector_type(4))) short bf16x4;
typedef __attribute__((ext_vector_type(4))) float f32x4;

__device__ __forceinline__ short f2bs(float f) {
    union { float f; unsigned u; } v; v.f = f;
    unsigned r = v.u + 0x7FFF + ((v.u >> 16) & 1);   // RNE to bf16
    return (short)(r >> 16);
}
__device__ __forceinline__ float bs2f(short s) {
    union { unsigned u; float f; } v; v.u = ((unsigned)(unsigned short)s) << 16;
    return v.f;
}
// single-instruction 2^x (exp2f lowers to the slow precise OCML path; v_exp_f32 IS 2^x)
__device__ __forceinline__ float fexp2(float x) {
    float r; asm("v_exp_f32 %0, %1" : "=v"(r) : "v"(x)); return r;
}
// async 16B/lane global->LDS (lds dst = wave-uniform base + lane*16)
__device__ __forceinline__ void gl2lds16(const short* g, short* l) {
    __builtin_amdgcn_global_load_lds(
        (const __attribute__((address_space(1))) unsigned int*)g,
        (__attribute__((address_space(3))) unsigned int*)l, 16, 0, 0);
}
// XCD-aware bijective remap (T1): XCD x gets contiguous orig-work range.
// REQUIRES nwg % 8 == 0 (all grids here: 576/768/384).
__device__ __forceinline__ unsigned xcd_swz(unsigned d, unsigned nwg) {
    return (d & 7) * (nwg >> 3) + (d >> 3);
}

// ---------------------------------------------------------------------------
// Prep: batched transpose+cvt. Wt[n*K+k] = bf16(W[k*N+n]).
// ---------------------------------------------------------------------------
struct TJobs { const float* src[8]; short* dst[8]; };

__global__ __launch_bounds__(256)
void transpose_cvt_batch(TJobs jobs, int K, int N)
{
    const float* __restrict__ W  = jobs.src[blockIdx.z];
    short* __restrict__ Wt = jobs.dst[blockIdx.z];
    __shared__ short tile[32][33];
    const int k0 = blockIdx.x * 32, n0 = blockIdx.y * 32;
    const int tx = threadIdx.x & 31, ty = threadIdx.x >> 5;
#pragma unroll
    for (int i = 0; i < 4; i++)
        tile[ty + i*8][tx] = f2bs(W[(size_t)(k0 + ty + i*8) * N + n0 + tx]);
    __syncthreads();
#pragma unroll
    for (int i = 0; i < 4; i++)
        Wt[(size_t)(n0 + ty + i*8) * K + k0 + tx] = tile[tx][ty + i*8];
}

// Prep: dst = bf16(src)
__global__ __launch_bounds__(256)
void cvt_bf16(const float* __restrict__ src, short* __restrict__ dst, int n)
{
    const int i = blockIdx.x * 256 + threadIdx.x;
    if (i < n) dst[i] = f2bs(src[i]);
}

// Prep: bqkv[l*2304 + {0|768|1536} + c] = {bq|bk|bv}[l*768 + c]
__global__ __launch_bounds__(256)
void pack_bias(const float* __restrict__ bq, const float* __restrict__ bk,
               const float* __restrict__ bv, float* __restrict__ bqkv)
{
    const int t = blockIdx.x * 256 + threadIdx.x;
    if (t >= NLAYER * 2304) return;
    const int l = t / 2304, r = t % 2304;
    const float* src = (r < 768) ? bq : (r < 1536 ? bk : bv);
    bqkv[t] = src[l*768 + (r % 768)];
}

// ---------------------------------------------------------------------------
// Prep: bias+mask in SWAPPED (S^T) MFMA C-fragment order, LOG2-DOMAIN:
// value = (bias*coef + (1-mask)*(-10000)) * log2(e)   [pairs with Q*0.125*log2e]
// ---------------------------------------------------------------------------
__global__ __launch_bounds__(256)
void bias_frag_prep(const float* __restrict__ biasM, const float* __restrict__ mask,
                    const float* __restrict__ coefp, short* __restrict__ bFrag)
{
    __shared__ float tile[64][129];   // 33 KB
    const int tid = threadIdx.x;
    const int qb = blockIdx.x, q0 = qb*64, k0 = blockIdx.y*128;
#pragma unroll
    for (int p = 0; p < 8; p++) {
        const int row = p*8 + (tid >> 5);
        const int col = (tid & 31) * 4;
        float4 v = *(const float4*)&biasM[(size_t)(q0 + row)*SS + k0 + col];
        tile[row][col+0] = v.x; tile[row][col+1] = v.y;
        tile[row][col+2] = v.z; tile[row][col+3] = v.w;
    }
    __syncthreads();
    const float coef = coefp[0];
    const int lane = tid & 63, w = tid >> 6;
    const int l16 = lane & 15, g = lane >> 4;
    const int qrow = w*16 + l16;
#pragma unroll
    for (int b = 0; b < BB; b++) {
#pragma unroll
        for (int kt = 0; kt < 8; kt++) {
            bf16x4 o;
#pragma unroll
            for (int r = 0; r < 4; r++) {
                const int kk = kt*16 + g*4 + r;
                const float madd = (1.f - mask[b*SS + k0 + kk]) * (-10000.0f);
                o[r] = f2bs((tile[qrow][kk] * coef + madd) * LOG2E);
            }
            const size_t idx = ((((size_t)b*32 + qb)*4 + w)*128 + (k0>>4) + kt)*256 + lane*4;
            *(bf16x4*)&bFrag[idx] = o;
        }
    }
}

// ---------------------------------------------------------------------------
// C[M,N](bf16) = act(A[M,K](bf16) @ Bt[N,K](bf16)^T + bias[N](f32))
// 128x128 tile, 4 waves, 16x16x32 MFMA, global_load_lds, BK=64 dual-buffer.
// R8: XCD-swizzled block mapping (contiguous M-panels per XCD; B L2-resident).
// Cols >= vsplit are written TRANSPOSED to VtOut[col-vsplit][row] (short4).
// Cols <  qcols get *qscale after bias (Q pre-scaling for log2-softmax).
// ---------------------------------------------------------------------------
__global__ __launch_bounds__(256)
void gemm_mfma(const short* __restrict__ A, const short* __restrict__ Bt,
               const float* __restrict__ bias, short* __restrict__ C, int ldc,
               int M, int N, int K, int gelu, short* __restrict__ VtOut, int vsplit,
               float qscale, int qcols)
{
    __shared__ short sA[2][128*32];   // 32 KB total
    __shared__ short sB[2][128*32];
    const int tid  = threadIdx.x;
    const int w    = tid >> 6;
    const int lane = tid & 63;
    const int l16  = lane & 15, g = lane >> 4;
    const int wm   = w & 1, wn = w >> 1;
    const unsigned wid = xcd_swz(blockIdx.y*gridDim.x + blockIdx.x,
                                 gridDim.x*gridDim.y);
    const size_t m0 = (size_t)(wid / gridDim.x) * 128;
    const size_t n0 = (size_t)(wid % gridDim.x) * 128;

    const int srow = lane >> 2;
    const int kc   = lane & 3;

    f32x4 acc[4][4];
#pragma unroll
    for (int i = 0; i < 4; i++)
#pragma unroll
        for (int j = 0; j < 4; j++) acc[i][j] = (f32x4){0.f,0.f,0.f,0.f};

    const short* gA0 = A  + (m0 + w*32 +      srow) * (size_t)K + kc*8;
    const short* gA1 = A  + (m0 + w*32 + 16 + srow) * (size_t)K + kc*8;
    const short* gB0 = Bt + (n0 + w*32 +      srow) * (size_t)K + kc*8;
    const short* gB1 = Bt + (n0 + w*32 + 16 + srow) * (size_t)K + kc*8;
    const int oA0 = (w*32     )*32, oA1 = (w*32 + 16)*32;

    for (int k0 = 0; k0 < K; k0 += 64) {
        gl2lds16(gA0 + k0,      &sA[0][oA0]);
        gl2lds16(gA1 + k0,      &sA[0][oA1]);
        gl2lds16(gB0 + k0,      &sB[0][oA0]);
        gl2lds16(gB1 + k0,      &sB[0][oA1]);
        gl2lds16(gA0 + k0 + 32, &sA[1][oA0]);
        gl2lds16(gA1 + k0 + 32, &sA[1][oA1]);
        gl2lds16(gB0 + k0 + 32, &sB[1][oA0]);
        gl2lds16(gB1 + k0 + 32, &sB[1][oA1]);
        __syncthreads();

#pragma unroll
        for (int s = 0; s < 2; s++) {
            bf16x8 af[4], bfr[4];
#pragma unroll
            for (int mt = 0; mt < 4; mt++)
                af[mt] = *(const bf16x8*)&sA[s][(wm*64 + mt*16 + l16)*32 + g*8];
#pragma unroll
            for (int nt = 0; nt < 4; nt++)
                bfr[nt] = *(const bf16x8*)&sB[s][(wn*64 + nt*16 + l16)*32 + g*8];
#pragma unroll
            for (int mt = 0; mt < 4; mt++)
#pragma unroll
                for (int nt = 0; nt < 4; nt++)
                    acc[mt][nt] = __builtin_amdgcn_mfma_f32_16x16x32_bf16(
                                      af[mt], bfr[nt], acc[mt][nt], 0, 0, 0);
        }
        __syncthreads();
    }

#pragma unroll
    for (int mt = 0; mt < 4; mt++) {
        const size_t row0 = m0 + wm*64 + mt*16 + g*4;
#pragma unroll
        for (int nt = 0; nt < 4; nt++) {
            const size_t col = n0 + wn*64 + nt*16 + l16;
            if ((int)col >= vsplit) {           // V part -> transposed bf16 out
                short4 t;
                t.x = f2bs(acc[mt][nt][0] + bias[col]);
                t.y = f2bs(acc[mt][nt][1] + bias[col]);
                t.z = f2bs(acc[mt][nt][2] + bias[col]);
                t.w = f2bs(acc[mt][nt][3] + bias[col]);
                *(short4*)&VtOut[(size_t)(col - vsplit)*MTOK + row0] = t;
            } else {
#pragma unroll
                for (int r = 0; r < 4; r++) {
                    float v = acc[mt][nt][r] + bias[col];
                    if ((int)col < qcols) v *= qscale;
                    if (gelu) v = 0.5f * v * (1.f + erff(v * 0.70710678118f));
                    C[(row0 + r) * (size_t)ldc + col] = f2bs(v);
                }
            }
        }
    }
}

// ---------------------------------------------------------------------------
// SPLIT-K=2 variant for the N=768 GEMMs (AO: K=768, FFN2: K=3072).
// grid (N/64, M/128, 2) = 768 blocks = 3/CU. XCD-swizzled within each z-plane.
// Writes f32 PARTIALS (no bias) to P[z][row][col]; add_ln3 fuses the sum.
// ---------------------------------------------------------------------------
__global__ __launch_bounds__(256)
void gemm_n64_splitk(const short* __restrict__ A, const short* __restrict__ Bt,
                     float* __restrict__ P, int K)
{
    const int K2 = K >> 1;
    const int z  = blockIdx.z;
    __shared__ short sA[2][128*32];   // 32 KB
    __shared__ short sB[2][64*32];    // 16 KB
    const int tid  = threadIdx.x;
    const int w    = tid >> 6;
    const int lane = tid & 63;
    const int l16  = lane & 15, g = lane >> 4;
    const int wm   = w & 1, wn = w >> 1;
    const unsigned wid = xcd_swz(blockIdx.y*gridDim.x + blockIdx.x,
                                 gridDim.x*gridDim.y);
    const size_t m0 = (size_t)(wid / gridDim.x) * 128;
    const size_t n0 = (size_t)(wid % gridDim.x) * 64;

    const int srow = lane >> 2;
    const int kc   = lane & 3;

    f32x4 acc[4][2];
#pragma unroll
    for (int i = 0; i < 4; i++)
#pragma unroll
        for (int j = 0; j < 2; j++) acc[i][j] = (f32x4){0.f,0.f,0.f,0.f};

    const short* gA0 = A  + (m0 + w*32 +      srow) * (size_t)K + z*K2 + kc*8;
    const short* gA1 = A  + (m0 + w*32 + 16 + srow) * (size_t)K + z*K2 + kc*8;
    const short* gB0 = Bt + (n0 + w*16 +      srow) * (size_t)K + z*K2 + kc*8;
    const int oA0 = (w*32     )*32, oA1 = (w*32 + 16)*32, oB0 = (w*16)*32;

    for (int k0 = 0; k0 < K2; k0 += 64) {
        gl2lds16(gA0 + k0,      &sA[0][oA0]);
        gl2lds16(gA1 + k0,      &sA[0][oA1]);
        gl2lds16(gB0 + k0,      &sB[0][oB0]);
        gl2lds16(gA0 + k0 + 32, &sA[1][oA0]);
        gl2lds16(gA1 + k0 + 32, &sA[1][oA1]);
        gl2lds16(gB0 + k0 + 32, &sB[1][oB0]);
        __syncthreads();

#pragma unroll
        for (int s = 0; s < 2; s++) {
            bf16x8 af[4], bfr[2];
#pragma unroll
            for (int mt = 0; mt < 4; mt++)
                af[mt] = *(const bf16x8*)&sA[s][(wm*64 + mt*16 + l16)*32 + g*8];
#pragma unroll
            for (int nt = 0; nt < 2; nt++)
                bfr[nt] = *(const bf16x8*)&sB[s][(wn*32 + nt*16 + l16)*32 + g*8];
#pragma unroll
            for (int mt = 0; mt < 4; mt++)
#pragma unroll
                for (int nt = 0; nt < 2; nt++)
                    acc[mt][nt] = __builtin_amdgcn_mfma_f32_16x16x32_bf16(
                                      af[mt], bfr[nt], acc[mt][nt], 0, 0, 0);
        }
        __syncthreads();
    }

    float* Pz = P + (size_t)z * MTOK * HH;
#pragma unroll
    for (int mt = 0; mt < 4; mt++) {
        const size_t row0 = m0 + wm*64 + mt*16 + g*4;
#pragma unroll
        for (int nt = 0; nt < 2; nt++) {
            const size_t col = n0 + wn*32 + nt*16 + l16;
#pragma unroll
            for (int r = 0; r < 4; r++)
                Pz[(row0 + r) * (size_t)HH + col] = acc[mt][nt][r];
        }
    }
}

// ---------------------------------------------------------------------------
// Flash attention, 128-key tiles, swapped QK^T (S^T = mfma(K,Q)), log2-domain.
// R8 = R6's MEASURED-BEST skeleton (sV staged via LDS, next-tile register
// prefetch, 2 barriers/tile; V-direct failed in R2 AND R5; KV-split failed
// in R7 on partial-O traffic) + defer-max (R7-verified bit-exact) +
// XCD-swizzled block mapping (contiguous (b,h) groups per XCD: K/V 1.5 MB
// L2-resident).
// ---------------------------------------------------------------------------
__global__ __launch_bounds__(256, 3)
void attn_fused(const short* __restrict__ QK, const short* __restrict__ Vt,
                const short* __restrict__ bFrag, short* __restrict__ CTX)
{
    __shared__ short sK[128*72];    // 18.4 KB  [key][dim]
    __shared__ short sV[64*136];    // 17.4 KB  [dim][key]

    // XCD swizzle: orig linear = (b*NHEAD + h)*32 + qb, nwg = 768
    const unsigned w3 = xcd_swz((blockIdx.z*gridDim.y + blockIdx.y)*gridDim.x
                                + blockIdx.x, 768);
    const int qb  = w3 & 31;
    const int h   = (w3 >> 5) % NHEAD;
    const int b   = (int)(w3 >> 5) / NHEAD;
    const int q0  = qb * 64;
    const int tid = threadIdx.x;
    const int w   = tid >> 6;
    const int lane = tid & 63;
    const int l16 = lane & 15;
    const int g   = lane >> 4;

    // Q B-frags (held all kernel; already scaled by 0.125*log2e)
    const short* qrow = QK + ((size_t)(b*SS) + q0 + w*16 + l16) * 1536 + h*64;
    bf16x8 bQ0 = *(const bf16x8*)(qrow + g*8);
    bf16x8 bQ1 = *(const bf16x8*)(qrow + 32 + g*8);

    f32x4 O[4];
#pragma unroll
    for (int d = 0; d < 4; d++) O[d] = (f32x4){0.f,0.f,0.f,0.f};
    float m_q = -1e30f, l_q = 0.f;   // per-lane online-softmax state, q = l16

    // staging maps: consecutive lanes cover one contiguous row
    const int krow = tid >> 3, kch = tid & 7;     // K: 32 rows x 8 chunks /pass
    const int vrow = tid >> 4, vch = tid & 15;    // V: 16 rows x 16 chunks /pass
    const short* Kg = QK + ((size_t)(b*SS) + krow)*1536 + 768 + h*64 + kch*8;
    const short* Vg = Vt + ((size_t)(h*64 + vrow))*MTOK + b*SS + vch*8;
    // bias frags: per wave, per k-subtile: one coalesced bf16x4 at lane*4
    const short* bF = bFrag + ((((size_t)b*32 + qb)*4 + w)*128)*256 + lane*4;

    // prologue prefetch (tile 0)
    bf16x8 kreg[4], vreg[4];
#pragma unroll
    for (int p = 0; p < 4; p++) {
        kreg[p] = *(const bf16x8*)(Kg + (size_t)(p*32)*1536);
        vreg[p] = *(const bf16x8*)(Vg + (size_t)(p*16)*MTOK);
    }

    for (int k0 = 0; k0 < SS; k0 += 128) {
        // ---- bias frags for this tile (independent of LDS) ----
        const short* bFt = bF + ((size_t)(k0 >> 4))*256;
        bf16x4 bb[8];
#pragma unroll
        for (int t = 0; t < 8; t++)
            bb[t] = *(const bf16x4*)(bFt + (size_t)t*256);

        // ---- staged regs -> LDS ----
#pragma unroll
        for (int p = 0; p < 4; p++) {
            *(bf16x8*)&sK[(p*32 + krow)*72 + kch*8]   = kreg[p];
            *(bf16x8*)&sV[(p*16 + vrow)*136 + vch*8]  = vreg[p];
        }
        __syncthreads();

        // ---- prefetch next tile (overlaps with compute below) ----
        if (k0 + 128 < SS) {
#pragma unroll
            for (int p = 0; p < 4; p++) {
                kreg[p] = *(const bf16x8*)(Kg + (size_t)(k0 + 128 + p*32)*1536);
                vreg[p] = *(const bf16x8*)(Vg + (size_t)(p*16)*MTOK + k0 + 128);
            }
        }

        // ---- S^T = K Q'^T + bias frag (log2-domain) ----
        float S[8][4];
#pragma unroll
        for (int t = 0; t < 8; t++) {
            bf16x8 aK0 = *(const bf16x8*)&sK[(t*16 + l16)*72 + g*8];
            bf16x8 aK1 = *(const bf16x8*)&sK[(t*16 + l16)*72 + 32 + g*8];
            f32x4 c = (f32x4){0.f,0.f,0.f,0.f};
            c = __builtin_amdgcn_mfma_f32_16x16x32_bf16(aK0, bQ0, c, 0, 0, 0);
            c = __builtin_amdgcn_mfma_f32_16x16x32_bf16(aK1, bQ1, c, 0, 0, 0);
#pragma unroll
            for (int r = 0; r < 4; r++)
                S[t][r] = c[r] + bs2f(bb[t][r]);
        }

        // ---- online softmax (base-2): per-lane trees + 2 shuffles ----
        float tm[8];
#pragma unroll
        for (int t = 0; t < 8; t++)
            tm[t] = fmaxf(fmaxf(S[t][0], S[t][1]), fmaxf(S[t][2], S[t][3]));
        float mx = fmaxf(fmaxf(fmaxf(tm[0], tm[1]), fmaxf(tm[2], tm[3])),
                         fmaxf(fmaxf(tm[4], tm[5]), fmaxf(tm[6], tm[7])));
        mx = fmaxf(mx, __shfl_xor(mx, 16));
        mx = fmaxf(mx, __shfl_xor(mx, 32));

        // defer-max (bit-exact): if NO q-row grew, alpha==1 -> skip rescale
        const bool grow = !__all(mx <= m_q);
        const float mnew = grow ? fmaxf(m_q, mx) : m_q;

        float ts[8];
#pragma unroll
        for (int t = 0; t < 8; t++) {
            float p0 = fexp2(S[t][0] - mnew);
            float p1 = fexp2(S[t][1] - mnew);
            float p2 = fexp2(S[t][2] - mnew);
            float p3 = fexp2(S[t][3] - mnew);
            S[t][0] = p0; S[t][1] = p1; S[t][2] = p2; S[t][3] = p3;
            ts[t] = (p0 + p1) + (p2 + p3);
        }
        float rs = ((ts[0] + ts[1]) + (ts[2] + ts[3]))
                 + ((ts[4] + ts[5]) + (ts[6] + ts[7]));
        rs += __shfl_xor(rs, 16);
        rs += __shfl_xor(rs, 32);

        if (grow) {
            const float alpha = fexp2(m_q - mnew);
            l_q = l_q * alpha + rs;
            m_q = mnew;
            // rescale O (O rows live at q = g*4+r; alpha lives at q = l16)
#pragma unroll
            for (int r = 0; r < 4; r++) {
                const float ar = __shfl(alpha, g*4 + r);
#pragma unroll
                for (int d = 0; d < 4; d++) O[d][r] *= ar;
            }
        } else {
            l_q += rs;
        }

        // ---- PV: in-register P frags x sV B-frags ----
#define PVU(u)                                                                 \
        {                                                                      \
            unsigned pa, pb, pc, pe;                                           \
            asm("v_cvt_pk_bf16_f32 %0, %1, %2" : "=v"(pa)                      \
                : "v"(S[2*(u)][0]),   "v"(S[2*(u)][1]));                       \
            asm("v_cvt_pk_bf16_f32 %0, %1, %2" : "=v"(pb)                      \
                : "v"(S[2*(u)][2]),   "v"(S[2*(u)][3]));                       \
            asm("v_cvt_pk_bf16_f32 %0, %1, %2" : "=v"(pc)                      \
                : "v"(S[2*(u)+1][0]), "v"(S[2*(u)+1][1]));                     \
            asm("v_cvt_pk_bf16_f32 %0, %1, %2" : "=v"(pe)                      \
                : "v"(S[2*(u)+1][2]), "v"(S[2*(u)+1][3]));                     \
            asm("v_permlane32_swap_b32 %0, %1" : "+v"(pa), "+v"(pc));          \
            asm("v_permlane16_swap_b32 %0, %1" : "+v"(pa), "+v"(pc));          \
            asm("v_permlane32_swap_b32 %0, %1" : "+v"(pb), "+v"(pe));          \
            asm("v_permlane16_swap_b32 %0, %1" : "+v"(pb), "+v"(pe));          \
            union { unsigned uw[4]; bf16x8 v; } P_;                            \
            P_.uw[0] = pa; P_.uw[1] = pb; P_.uw[2] = pc; P_.uw[3] = pe;        \
            _Pragma("unroll")                                                  \
            for (int d = 0; d < 4; d++) {                                      \
                bf16x8 vv = *(const bf16x8*)&sV[(d*16 + l16)*136 + (u)*32 + g*8]; \
                O[d] = __builtin_amdgcn_mfma_f32_16x16x32_bf16(                \
                           P_.v, vv, O[d], 0, 0, 0);                           \
            }                                                                  \
        }
        PVU(0)
        PVU(1)
        PVU(2)
        PVU(3)
#undef PVU

        __syncthreads();   // before next tile restages sK/sV
    }

    float linv[4];
#pragma unroll
    for (int r = 0; r < 4; r++)
        linv[r] = 1.f / __shfl(l_q, g*4 + r);
#pragma unroll
    for (int d = 0; d < 4; d++)
#pragma unroll
        for (int r = 0; r < 4; r++)
            CTX[((size_t)(b*SS) + q0 + w*16 + g*4 + r)*HH + h*64 + d*16 + l16]
                = f2bs(O[d][r] * linv[r]);
}

// ---------------------------------------------------------------------------
// Out(bf16) = LayerNorm(P0 + P1 + bias + R) * g + beta; optional fp32 OutF.
// P = two f32 split-K partials [2][MTOK][HH]; R = bf16 residual.
// One WAVE per row, shfl-only reductions.
// ---------------------------------------------------------------------------
__global__ __launch_bounds__(256)
void add_ln3(const float* __restrict__ P, const float* __restrict__ bvec,
             const short* __restrict__ R,
             const float* __restrict__ g, const float* __restrict__ beta,
             short* __restrict__ Out, float* __restrict__ OutF)
{
    const int lane = threadIdx.x & 63;
    const int row  = blockIdx.x * 4 + (threadIdx.x >> 6);
    const size_t base = (size_t)row * HH;
    const size_t sH = (size_t)MTOK * HH;

    float v[12];
    float s = 0.f;
#pragma unroll
    for (int p = 0; p < 3; p++) {
        const int c = p*256 + lane*4;
        float4 p0 = *(const float4*)&P[base + c];
        float4 p1 = *(const float4*)&P[sH + base + c];
        float4 bv4 = *(const float4*)&bvec[c];
        bf16x4 rv = *(const bf16x4*)&R[base + c];
        float x0 = p0.x + p1.x + bv4.x + bs2f(rv[0]);
        float x1 = p0.y + p1.y + bv4.y + bs2f(rv[1]);
        float x2 = p0.z + p1.z + bv4.z + bs2f(rv[2]);
        float x3 = p0.w + p1.w + bv4.w + bs2f(rv[3]);
        v[p*4+0] = x0; v[p*4+1] = x1; v[p*4+2] = x2; v[p*4+3] = x3;
        s += (x0 + x1) + (x2 + x3);
    }
    s += __shfl_xor(s, 1);  s += __shfl_xor(s, 2);  s += __shfl_xor(s, 4);
    s += __shfl_xor(s, 8);  s += __shfl_xor(s, 16); s += __shfl_xor(s, 32);
    const float mu = s * (1.f / HH);

    float s2 = 0.f;
#pragma unroll
    for (int j = 0; j < 12; j++) { float d = v[j] - mu; s2 += d * d; }
    s2 += __shfl_xor(s2, 1);  s2 += __shfl_xor(s2, 2);  s2 += __shfl_xor(s2, 4);
    s2 += __shfl_xor(s2, 8);  s2 += __shfl_xor(s2, 16); s2 += __shfl_xor(s2, 32);
    const float rstd = rsqrtf(s2 * (1.f / HH) + 1e-12f);

#pragma unroll
    for (int p = 0; p < 3; p++) {
        const int c = p*256 + lane*4;
        float4 gv = *(const float4*)&g[c];
        float4 bv = *(const float4*)&beta[c];
        float o0 = (v[p*4+0] - mu) * rstd * gv.x + bv.x;
        float o1 = (v[p*4+1] - mu) * rstd * gv.y + bv.y;
        float o2 = (v[p*4+2] - mu) * rstd * gv.z + bv.z;
        float o3 = (v[p*4+3] - mu) * rstd * gv.w + bv.w;
        bf16x4 ov; ov[0] = f2bs(o0); ov[1] = f2bs(o1); ov[2] = f2bs(o2); ov[3] = f2bs(o3);
        *(bf16x4*)&Out[base + c] = ov;
        if (OutF) {
            float4 of; of.x = o0; of.y = o1; of.z = o2; of.w = o3;
            *(float4*)&OutF[base + c] = of;
        }
    }
}

// ---------------------------------------------------------------------------
extern "C" void kernel_launch(void* const* d_in, const int* in_sizes, int n_in,
                              void* d_out, int out_size, void* d_ws, size_t ws_size,
                              hipStream_t stream)
{
    const float* hs    = (const float*)d_in[0];
    const float* mask  = (const float*)d_in[1];
    const float* biasM = (const float*)d_in[2];
    const float* coef  = (const float*)d_in[3];
    const float* Wq    = (const float*)d_in[4];
    const float* bq    = (const float*)d_in[5];
    const float* Wk    = (const float*)d_in[6];
    const float* bk    = (const float*)d_in[7];
    const float* Wv    = (const float*)d_in[8];
    const float* bv    = (const float*)d_in[9];
    const float* Wo    = (const float*)d_in[10];
    const float* bo    = (const float*)d_in[11];
    const float* ln1g  = (const float*)d_in[12];
    const float* ln1b  = (const float*)d_in[13];
    const float* Wi    = (const float*)d_in[14];
    const float* bi    = (const float*)d_in[15];
    const float* Wo2   = (const float*)d_in[16];
    const float* bo2   = (const float*)d_in[17];
    const float* ln2g  = (const float*)d_in[18];
    const float* ln2b  = (const float*)d_in[19];

    // ---- workspace (~108 MB; 138 MB proven available) ----
    const size_t sH   = (size_t)MTOK * HH;
    const size_t sQK  = (size_t)MTOK * 1536;
    const size_t sVt  = (size_t)HH * MTOK;
    const size_t WPL  = 7077888;
    short* wt    = (short*)d_ws;
    float* bqkv  = (float*)(wt + 2*WPL);
    short* bFrag = (short*)(bqkv + 2*2304);       // [2*SS*SS] bias+mask C-frags
    short* X     = bFrag + (size_t)2*SS*SS;
    short* X2    = X  + sH;
    short* QK    = X2 + sH;
    short* Vt    = QK + sQK;
    short* CTX   = Vt + sVt;
    float* PK    = (float*)(CTX + sH);            // [2][MTOK][HH] f32 partials
    short* INTER = QK;

    const dim3 blk(256);

    // ---- prep: batched transposes, bias frags, bias pack, hs cvt ----
    TJobs jH, jI, jO;
    for (int l = 0; l < NLAYER; l++) {
        short* wl = wt + (size_t)l * WPL;
        jH.src[l*4+0] = Wq + (size_t)l*HH*HH;  jH.dst[l*4+0] = wl;
        jH.src[l*4+1] = Wk + (size_t)l*HH*HH;  jH.dst[l*4+1] = wl + 768*768;
        jH.src[l*4+2] = Wv + (size_t)l*HH*HH;  jH.dst[l*4+2] = wl + 1536*768;
        jH.src[l*4+3] = Wo + (size_t)l*HH*HH;  jH.dst[l*4+3] = wl + 1769472;
        jI.src[l] = Wi  + (size_t)l*HH*FFD;    jI.dst[l] = wl + 2359296;
        jO.src[l] = Wo2 + (size_t)l*FFD*HH;    jO.dst[l] = wl + 4718592;
    }
    transpose_cvt_batch<<<dim3(24,24,8), blk, 0, stream>>>(jH, HH, HH);
    transpose_cvt_batch<<<dim3(24,96,2), blk, 0, stream>>>(jI, HH, FFD);
    transpose_cvt_batch<<<dim3(96,24,2), blk, 0, stream>>>(jO, FFD, HH);
    bias_frag_prep<<<dim3(SS/64, SS/128), blk, 0, stream>>>(biasM, mask, coef, bFrag);
    pack_bias<<<dim3((NLAYER*2304 + 255)/256), blk, 0, stream>>>(bq, bk, bv, bqkv);
    cvt_bf16<<<dim3((int)((sH + 255)/256)), blk, 0, stream>>>(hs, X, (int)sH);

    const dim3 gQKV(2304/128, MTOK/128);      // [18, 32] = 576
    const dim3 gSK (HH/64,    MTOK/128, 2);   // [12, 32, 2] split-K (384/plane)
    const dim3 gFF (FFD/128,  MTOK/128);      // [24, 32] = 768
    const dim3 gA  (SS/64, NHEAD, BB);        // [32, 12, 2] = 768 blocks
    const dim3 gLN (MTOK/4);                  // wave-per-row LN
    const int NOSPLIT = 1 << 30;

    for (int l = 0; l < NLAYER; l++) {
        short* wl = wt + (size_t)l * WPL;
        gemm_mfma<<<gQKV, blk, 0, stream>>>(X, wl, bqkv + l*2304, QK, 1536,
                                            MTOK, 2304, HH, 0, Vt, 1536,
                                            QSCALE, 768);
        attn_fused<<<gA, blk, 0, stream>>>(QK, Vt, bFrag, CTX);
        gemm_n64_splitk<<<gSK, blk, 0, stream>>>(CTX, wl + 1769472, PK, HH);
        add_ln3<<<gLN, blk, 0, stream>>>(PK, bo + l*HH, X, ln1g + l*HH, ln1b + l*HH,
                                         X2, nullptr);
        gemm_mfma<<<gFF, blk, 0, stream>>>(X2, wl + 2359296, bi + l*FFD, INTER, FFD,
                                           MTOK, FFD, HH, 1, nullptr, NOSPLIT,
                                           1.f, 0);
        gemm_n64_splitk<<<gSK, blk, 0, stream>>>(INTER, wl + 4718592, PK, FFD);
        add_ln3<<<gLN, blk, 0, stream>>>(PK, bo2 + l*HH, X2, ln2g + l*HH, ln2b + l*HH,
                                         X, (l == NLAYER-1) ? (float*)d_out : nullptr);
    }
}

// Round 9
// 526.901 us; speedup vs baseline: 1.0950x; 1.0242x over previous
//
#include <hip/hip_runtime.h>
#include <hip/hip_bf16.h>
#include <math.h>

#define BB     2
#define SS     2048
#define HH     768
#define NHEAD  12
#define DHEAD  64
#define FFD    3072
#define NLAYER 2
#define MTOK   (BB*SS)   // 4096 rows
#define LOG2E  1.4426950408889634f
#define QSCALE 0.18033688011112042f   // 0.125 * log2(e)

typedef __attribute__((ext_vector_type(8))) short bf16x8;
typedef __attribute__((ext_vector_type(4))) short bf16x4;
typedef __attribute__((ext_vector_type(4))) float f32x4;

__device__ __forceinline__ short f2bs(float f) {
    union { float f; unsigned u; } v; v.f = f;
    unsigned r = v.u + 0x7FFF + ((v.u >> 16) & 1);   // RNE to bf16
    return (short)(r >> 16);
}
__device__ __forceinline__ float bs2f(short s) {
    union { unsigned u; float f; } v; v.u = ((unsigned)(unsigned short)s) << 16;
    return v.f;
}
// single-instruction 2^x (exp2f lowers to the slow precise OCML path; v_exp_f32 IS 2^x)
__device__ __forceinline__ float fexp2(float x) {
    float r; asm("v_exp_f32 %0, %1" : "=v"(r) : "v"(x)); return r;
}
// async 16B/lane global->LDS (lds dst = wave-uniform base + lane*16)
__device__ __forceinline__ void gl2lds16(const short* g, short* l) {
    __builtin_amdgcn_global_load_lds(
        (const __attribute__((address_space(1))) unsigned int*)g,
        (__attribute__((address_space(3))) unsigned int*)l, 16, 0, 0);
}
// XCD-aware bijective remap (T1): XCD x gets contiguous orig-work range.
// REQUIRES nwg % 8 == 0. GEMMs only (attn is not BW-bound: R8 showed FETCH
// drop but dur regression there).
__device__ __forceinline__ unsigned xcd_swz(unsigned d, unsigned nwg) {
    return (d & 7) * (nwg >> 3) + (d >> 3);
}

// ---------------------------------------------------------------------------
// Prep: batched transpose+cvt. Wt[n*K+k] = bf16(W[k*N+n]).
// ---------------------------------------------------------------------------
struct TJobs { const float* src[8]; short* dst[8]; };

__global__ __launch_bounds__(256)
void transpose_cvt_batch(TJobs jobs, int K, int N)
{
    const float* __restrict__ W  = jobs.src[blockIdx.z];
    short* __restrict__ Wt = jobs.dst[blockIdx.z];
    __shared__ short tile[32][33];
    const int k0 = blockIdx.x * 32, n0 = blockIdx.y * 32;
    const int tx = threadIdx.x & 31, ty = threadIdx.x >> 5;
#pragma unroll
    for (int i = 0; i < 4; i++)
        tile[ty + i*8][tx] = f2bs(W[(size_t)(k0 + ty + i*8) * N + n0 + tx]);
    __syncthreads();
#pragma unroll
    for (int i = 0; i < 4; i++)
        Wt[(size_t)(n0 + ty + i*8) * K + k0 + tx] = tile[tx][ty + i*8];
}

// Prep: dst = bf16(src)
__global__ __launch_bounds__(256)
void cvt_bf16(const float* __restrict__ src, short* __restrict__ dst, int n)
{
    const int i = blockIdx.x * 256 + threadIdx.x;
    if (i < n) dst[i] = f2bs(src[i]);
}

// Prep: bqkv[l*2304 + {0|768|1536} + c] = {bq|bk|bv}[l*768 + c]
__global__ __launch_bounds__(256)
void pack_bias(const float* __restrict__ bq, const float* __restrict__ bk,
               const float* __restrict__ bv, float* __restrict__ bqkv)
{
    const int t = blockIdx.x * 256 + threadIdx.x;
    if (t >= NLAYER * 2304) return;
    const int l = t / 2304, r = t % 2304;
    const float* src = (r < 768) ? bq : (r < 1536 ? bk : bv);
    bqkv[t] = src[l*768 + (r % 768)];
}

// ---------------------------------------------------------------------------
// Prep: bias+mask in SWAPPED (S^T) MFMA C-fragment order, LOG2-DOMAIN:
// value = (bias*coef + (1-mask)*(-10000)) * log2(e)   [pairs with Q*0.125*log2e]
// ---------------------------------------------------------------------------
__global__ __launch_bounds__(256)
void bias_frag_prep(const float* __restrict__ biasM, const float* __restrict__ mask,
                    const float* __restrict__ coefp, short* __restrict__ bFrag)
{
    __shared__ float tile[64][129];   // 33 KB
    const int tid = threadIdx.x;
    const int qb = blockIdx.x, q0 = qb*64, k0 = blockIdx.y*128;
#pragma unroll
    for (int p = 0; p < 8; p++) {
        const int row = p*8 + (tid >> 5);
        const int col = (tid & 31) * 4;
        float4 v = *(const float4*)&biasM[(size_t)(q0 + row)*SS + k0 + col];
        tile[row][col+0] = v.x; tile[row][col+1] = v.y;
        tile[row][col+2] = v.z; tile[row][col+3] = v.w;
    }
    __syncthreads();
    const float coef = coefp[0];
    const int lane = tid & 63, w = tid >> 6;
    const int l16 = lane & 15, g = lane >> 4;
    const int qrow = w*16 + l16;
#pragma unroll
    for (int b = 0; b < BB; b++) {
#pragma unroll
        for (int kt = 0; kt < 8; kt++) {
            bf16x4 o;
#pragma unroll
            for (int r = 0; r < 4; r++) {
                const int kk = kt*16 + g*4 + r;
                const float madd = (1.f - mask[b*SS + k0 + kk]) * (-10000.0f);
                o[r] = f2bs((tile[qrow][kk] * coef + madd) * LOG2E);
            }
            const size_t idx = ((((size_t)b*32 + qb)*4 + w)*128 + (k0>>4) + kt)*256 + lane*4;
            *(bf16x4*)&bFrag[idx] = o;
        }
    }
}

// ---------------------------------------------------------------------------
// C[M,N](bf16) = act(A[M,K](bf16) @ Bt[N,K](bf16)^T + bias[N](f32))
// 128x128 tile, 4 waves, 16x16x32 MFMA, global_load_lds, BK=64 dual-buffer.
// XCD-swizzled block mapping (contiguous M-panels per XCD; B L2-resident).
// Cols >= vsplit are written TRANSPOSED to VtOut[col-vsplit][row] (short4).
// Cols <  qcols get *qscale after bias (Q pre-scaling for log2-softmax).
// ---------------------------------------------------------------------------
__global__ __launch_bounds__(256)
void gemm_mfma(const short* __restrict__ A, const short* __restrict__ Bt,
               const float* __restrict__ bias, short* __restrict__ C, int ldc,
               int M, int N, int K, int gelu, short* __restrict__ VtOut, int vsplit,
               float qscale, int qcols)
{
    __shared__ short sA[2][128*32];   // 32 KB total
    __shared__ short sB[2][128*32];
    const int tid  = threadIdx.x;
    const int w    = tid >> 6;
    const int lane = tid & 63;
    const int l16  = lane & 15, g = lane >> 4;
    const int wm   = w & 1, wn = w >> 1;
    const unsigned wid = xcd_swz(blockIdx.y*gridDim.x + blockIdx.x,
                                 gridDim.x*gridDim.y);
    const size_t m0 = (size_t)(wid / gridDim.x) * 128;
    const size_t n0 = (size_t)(wid % gridDim.x) * 128;

    const int srow = lane >> 2;
    const int kc   = lane & 3;

    f32x4 acc[4][4];
#pragma unroll
    for (int i = 0; i < 4; i++)
#pragma unroll
        for (int j = 0; j < 4; j++) acc[i][j] = (f32x4){0.f,0.f,0.f,0.f};

    const short* gA0 = A  + (m0 + w*32 +      srow) * (size_t)K + kc*8;
    const short* gA1 = A  + (m0 + w*32 + 16 + srow) * (size_t)K + kc*8;
    const short* gB0 = Bt + (n0 + w*32 +      srow) * (size_t)K + kc*8;
    const short* gB1 = Bt + (n0 + w*32 + 16 + srow) * (size_t)K + kc*8;
    const int oA0 = (w*32     )*32, oA1 = (w*32 + 16)*32;

    for (int k0 = 0; k0 < K; k0 += 64) {
        gl2lds16(gA0 + k0,      &sA[0][oA0]);
        gl2lds16(gA1 + k0,      &sA[0][oA1]);
        gl2lds16(gB0 + k0,      &sB[0][oA0]);
        gl2lds16(gB1 + k0,      &sB[0][oA1]);
        gl2lds16(gA0 + k0 + 32, &sA[1][oA0]);
        gl2lds16(gA1 + k0 + 32, &sA[1][oA1]);
        gl2lds16(gB0 + k0 + 32, &sB[1][oA0]);
        gl2lds16(gB1 + k0 + 32, &sB[1][oA1]);
        __syncthreads();

#pragma unroll
        for (int s = 0; s < 2; s++) {
            bf16x8 af[4], bfr[4];
#pragma unroll
            for (int mt = 0; mt < 4; mt++)
                af[mt] = *(const bf16x8*)&sA[s][(wm*64 + mt*16 + l16)*32 + g*8];
#pragma unroll
            for (int nt = 0; nt < 4; nt++)
                bfr[nt] = *(const bf16x8*)&sB[s][(wn*64 + nt*16 + l16)*32 + g*8];
#pragma unroll
            for (int mt = 0; mt < 4; mt++)
#pragma unroll
                for (int nt = 0; nt < 4; nt++)
                    acc[mt][nt] = __builtin_amdgcn_mfma_f32_16x16x32_bf16(
                                      af[mt], bfr[nt], acc[mt][nt], 0, 0, 0);
        }
        __syncthreads();
    }

#pragma unroll
    for (int mt = 0; mt < 4; mt++) {
        const size_t row0 = m0 + wm*64 + mt*16 + g*4;
#pragma unroll
        for (int nt = 0; nt < 4; nt++) {
            const size_t col = n0 + wn*64 + nt*16 + l16;
            if ((int)col >= vsplit) {           // V part -> transposed bf16 out
                short4 t;
                t.x = f2bs(acc[mt][nt][0] + bias[col]);
                t.y = f2bs(acc[mt][nt][1] + bias[col]);
                t.z = f2bs(acc[mt][nt][2] + bias[col]);
                t.w = f2bs(acc[mt][nt][3] + bias[col]);
                *(short4*)&VtOut[(size_t)(col - vsplit)*MTOK + row0] = t;
            } else {
#pragma unroll
                for (int r = 0; r < 4; r++) {
                    float v = acc[mt][nt][r] + bias[col];
                    if ((int)col < qcols) v *= qscale;
                    if (gelu) v = 0.5f * v * (1.f + erff(v * 0.70710678118f));
                    C[(row0 + r) * (size_t)ldc + col] = f2bs(v);
                }
            }
        }
    }
}

// ---------------------------------------------------------------------------
// SPLIT-K=2 variant for the N=768 GEMMs (AO: K=768, FFN2: K=3072).
// grid (N/64, M/128, 2) = 768 blocks = 3/CU. XCD-swizzled within each z-plane.
// Writes f32 PARTIALS (no bias) to P[z][row][col]; add_ln3 fuses the sum.
// ---------------------------------------------------------------------------
__global__ __launch_bounds__(256)
void gemm_n64_splitk(const short* __restrict__ A, const short* __restrict__ Bt,
                     float* __restrict__ P, int K)
{
    const int K2 = K >> 1;
    const int z  = blockIdx.z;
    __shared__ short sA[2][128*32];   // 32 KB
    __shared__ short sB[2][64*32];    // 16 KB
    const int tid  = threadIdx.x;
    const int w    = tid >> 6;
    const int lane = tid & 63;
    const int l16  = lane & 15, g = lane >> 4;
    const int wm   = w & 1, wn = w >> 1;
    const unsigned wid = xcd_swz(blockIdx.y*gridDim.x + blockIdx.x,
                                 gridDim.x*gridDim.y);
    const size_t m0 = (size_t)(wid / gridDim.x) * 128;
    const size_t n0 = (size_t)(wid % gridDim.x) * 64;

    const int srow = lane >> 2;
    const int kc   = lane & 3;

    f32x4 acc[4][2];
#pragma unroll
    for (int i = 0; i < 4; i++)
#pragma unroll
        for (int j = 0; j < 2; j++) acc[i][j] = (f32x4){0.f,0.f,0.f,0.f};

    const short* gA0 = A  + (m0 + w*32 +      srow) * (size_t)K + z*K2 + kc*8;
    const short* gA1 = A  + (m0 + w*32 + 16 + srow) * (size_t)K + z*K2 + kc*8;
    const short* gB0 = Bt + (n0 + w*16 +      srow) * (size_t)K + z*K2 + kc*8;
    const int oA0 = (w*32     )*32, oA1 = (w*32 + 16)*32, oB0 = (w*16)*32;

    for (int k0 = 0; k0 < K2; k0 += 64) {
        gl2lds16(gA0 + k0,      &sA[0][oA0]);
        gl2lds16(gA1 + k0,      &sA[0][oA1]);
        gl2lds16(gB0 + k0,      &sB[0][oB0]);
        gl2lds16(gA0 + k0 + 32, &sA[1][oA0]);
        gl2lds16(gA1 + k0 + 32, &sA[1][oA1]);
        gl2lds16(gB0 + k0 + 32, &sB[1][oB0]);
        __syncthreads();

#pragma unroll
        for (int s = 0; s < 2; s++) {
            bf16x8 af[4], bfr[2];
#pragma unroll
            for (int mt = 0; mt < 4; mt++)
                af[mt] = *(const bf16x8*)&sA[s][(wm*64 + mt*16 + l16)*32 + g*8];
#pragma unroll
            for (int nt = 0; nt < 2; nt++)
                bfr[nt] = *(const bf16x8*)&sB[s][(wn*32 + nt*16 + l16)*32 + g*8];
#pragma unroll
            for (int mt = 0; mt < 4; mt++)
#pragma unroll
                for (int nt = 0; nt < 2; nt++)
                    acc[mt][nt] = __builtin_amdgcn_mfma_f32_16x16x32_bf16(
                                      af[mt], bfr[nt], acc[mt][nt], 0, 0, 0);
        }
        __syncthreads();
    }

    float* Pz = P + (size_t)z * MTOK * HH;
#pragma unroll
    for (int mt = 0; mt < 4; mt++) {
        const size_t row0 = m0 + wm*64 + mt*16 + g*4;
#pragma unroll
        for (int nt = 0; nt < 2; nt++) {
            const size_t col = n0 + wn*32 + nt*16 + l16;
#pragma unroll
            for (int r = 0; r < 4; r++)
                Pz[(row0 + r) * (size_t)HH + col] = acc[mt][nt][r];
        }
    }
}

// ---------------------------------------------------------------------------
// Flash attention, 128-key tiles, swapped QK^T (S^T = mfma(K,Q)), log2-domain.
// R9 = R6 skeleton with NATURAL block mapping (R8's attn XCD-swizzle cut
// FETCH 8% but cost 1.3 us — attn is not BW-bound; reverted) + defer-max
// (kept, bit-exact) + T5 s_setprio(1) around MFMA clusters (m191: +4-7% attn;
// 3 independent blocks/CU at different phases give the scheduler something
// to arbitrate).
// ---------------------------------------------------------------------------
__global__ __launch_bounds__(256, 3)
void attn_fused(const short* __restrict__ QK, const short* __restrict__ Vt,
                const short* __restrict__ bFrag, short* __restrict__ CTX)
{
    __shared__ short sK[128*72];    // 18.4 KB  [key][dim]
    __shared__ short sV[64*136];    // 17.4 KB  [dim][key]

    const int qb  = blockIdx.x;
    const int q0  = qb * 64;
    const int h   = blockIdx.y;
    const int b   = blockIdx.z;
    const int tid = threadIdx.x;
    const int w   = tid >> 6;
    const int lane = tid & 63;
    const int l16 = lane & 15;
    const int g   = lane >> 4;

    // Q B-frags (held all kernel; already scaled by 0.125*log2e)
    const short* qrow = QK + ((size_t)(b*SS) + q0 + w*16 + l16) * 1536 + h*64;
    bf16x8 bQ0 = *(const bf16x8*)(qrow + g*8);
    bf16x8 bQ1 = *(const bf16x8*)(qrow + 32 + g*8);

    f32x4 O[4];
#pragma unroll
    for (int d = 0; d < 4; d++) O[d] = (f32x4){0.f,0.f,0.f,0.f};
    float m_q = -1e30f, l_q = 0.f;   // per-lane online-softmax state, q = l16

    // staging maps: consecutive lanes cover one contiguous row
    const int krow = tid >> 3, kch = tid & 7;     // K: 32 rows x 8 chunks /pass
    const int vrow = tid >> 4, vch = tid & 15;    // V: 16 rows x 16 chunks /pass
    const short* Kg = QK + ((size_t)(b*SS) + krow)*1536 + 768 + h*64 + kch*8;
    const short* Vg = Vt + ((size_t)(h*64 + vrow))*MTOK + b*SS + vch*8;
    // bias frags: per wave, per k-subtile: one coalesced bf16x4 at lane*4
    const short* bF = bFrag + ((((size_t)b*32 + qb)*4 + w)*128)*256 + lane*4;

    // prologue prefetch (tile 0)
    bf16x8 kreg[4], vreg[4];
#pragma unroll
    for (int p = 0; p < 4; p++) {
        kreg[p] = *(const bf16x8*)(Kg + (size_t)(p*32)*1536);
        vreg[p] = *(const bf16x8*)(Vg + (size_t)(p*16)*MTOK);
    }

    for (int k0 = 0; k0 < SS; k0 += 128) {
        // ---- bias frags for this tile (independent of LDS) ----
        const short* bFt = bF + ((size_t)(k0 >> 4))*256;
        bf16x4 bb[8];
#pragma unroll
        for (int t = 0; t < 8; t++)
            bb[t] = *(const bf16x4*)(bFt + (size_t)t*256);

        // ---- staged regs -> LDS ----
#pragma unroll
        for (int p = 0; p < 4; p++) {
            *(bf16x8*)&sK[(p*32 + krow)*72 + kch*8]   = kreg[p];
            *(bf16x8*)&sV[(p*16 + vrow)*136 + vch*8]  = vreg[p];
        }
        __syncthreads();

        // ---- prefetch next tile (overlaps with compute below) ----
        if (k0 + 128 < SS) {
#pragma unroll
            for (int p = 0; p < 4; p++) {
                kreg[p] = *(const bf16x8*)(Kg + (size_t)(k0 + 128 + p*32)*1536);
                vreg[p] = *(const bf16x8*)(Vg + (size_t)(p*16)*MTOK + k0 + 128);
            }
        }

        // ---- S^T = K Q'^T + bias frag (log2-domain), setprio'd MFMA ----
        float S[8][4];
        __builtin_amdgcn_s_setprio(1);
#pragma unroll
        for (int t = 0; t < 8; t++) {
            bf16x8 aK0 = *(const bf16x8*)&sK[(t*16 + l16)*72 + g*8];
            bf16x8 aK1 = *(const bf16x8*)&sK[(t*16 + l16)*72 + 32 + g*8];
            f32x4 c = (f32x4){0.f,0.f,0.f,0.f};
            c = __builtin_amdgcn_mfma_f32_16x16x32_bf16(aK0, bQ0, c, 0, 0, 0);
            c = __builtin_amdgcn_mfma_f32_16x16x32_bf16(aK1, bQ1, c, 0, 0, 0);
#pragma unroll
            for (int r = 0; r < 4; r++)
                S[t][r] = c[r] + bs2f(bb[t][r]);
        }
        __builtin_amdgcn_s_setprio(0);

        // ---- online softmax (base-2): per-lane trees + 2 shuffles ----
        float tm[8];
#pragma unroll
        for (int t = 0; t < 8; t++)
            tm[t] = fmaxf(fmaxf(S[t][0], S[t][1]), fmaxf(S[t][2], S[t][3]));
        float mx = fmaxf(fmaxf(fmaxf(tm[0], tm[1]), fmaxf(tm[2], tm[3])),
                         fmaxf(fmaxf(tm[4], tm[5]), fmaxf(tm[6], tm[7])));
        mx = fmaxf(mx, __shfl_xor(mx, 16));
        mx = fmaxf(mx, __shfl_xor(mx, 32));

        // defer-max (bit-exact): if NO q-row grew, alpha==1 -> skip rescale
        const bool grow = !__all(mx <= m_q);
        const float mnew = grow ? fmaxf(m_q, mx) : m_q;

        float ts[8];
#pragma unroll
        for (int t = 0; t < 8; t++) {
            float p0 = fexp2(S[t][0] - mnew);
            float p1 = fexp2(S[t][1] - mnew);
            float p2 = fexp2(S[t][2] - mnew);
            float p3 = fexp2(S[t][3] - mnew);
            S[t][0] = p0; S[t][1] = p1; S[t][2] = p2; S[t][3] = p3;
            ts[t] = (p0 + p1) + (p2 + p3);
        }
        float rs = ((ts[0] + ts[1]) + (ts[2] + ts[3]))
                 + ((ts[4] + ts[5]) + (ts[6] + ts[7]));
        rs += __shfl_xor(rs, 16);
        rs += __shfl_xor(rs, 32);

        if (grow) {
            const float alpha = fexp2(m_q - mnew);
            l_q = l_q * alpha + rs;
            m_q = mnew;
            // rescale O (O rows live at q = g*4+r; alpha lives at q = l16)
#pragma unroll
            for (int r = 0; r < 4; r++) {
                const float ar = __shfl(alpha, g*4 + r);
#pragma unroll
                for (int d = 0; d < 4; d++) O[d][r] *= ar;
            }
        } else {
            l_q += rs;
        }

        // ---- PV: in-register P frags x sV B-frags, setprio'd ----
        __builtin_amdgcn_s_setprio(1);
#define PVU(u)                                                                 \
        {                                                                      \
            unsigned pa, pb, pc, pe;                                           \
            asm("v_cvt_pk_bf16_f32 %0, %1, %2" : "=v"(pa)                      \
                : "v"(S[2*(u)][0]),   "v"(S[2*(u)][1]));                       \
            asm("v_cvt_pk_bf16_f32 %0, %1, %2" : "=v"(pb)                      \
                : "v"(S[2*(u)][2]),   "v"(S[2*(u)][3]));                       \
            asm("v_cvt_pk_bf16_f32 %0, %1, %2" : "=v"(pc)                      \
                : "v"(S[2*(u)+1][0]), "v"(S[2*(u)+1][1]));                     \
            asm("v_cvt_pk_bf16_f32 %0, %1, %2" : "=v"(pe)                      \
                : "v"(S[2*(u)+1][2]), "v"(S[2*(u)+1][3]));                     \
            asm("v_permlane32_swap_b32 %0, %1" : "+v"(pa), "+v"(pc));          \
            asm("v_permlane16_swap_b32 %0, %1" : "+v"(pa), "+v"(pc));          \
            asm("v_permlane32_swap_b32 %0, %1" : "+v"(pb), "+v"(pe));          \
            asm("v_permlane16_swap_b32 %0, %1" : "+v"(pb), "+v"(pe));          \
            union { unsigned uw[4]; bf16x8 v; } P_;                            \
            P_.uw[0] = pa; P_.uw[1] = pb; P_.uw[2] = pc; P_.uw[3] = pe;        \
            _Pragma("unroll")                                                  \
            for (int d = 0; d < 4; d++) {                                      \
                bf16x8 vv = *(const bf16x8*)&sV[(d*16 + l16)*136 + (u)*32 + g*8]; \
                O[d] = __builtin_amdgcn_mfma_f32_16x16x32_bf16(                \
                           P_.v, vv, O[d], 0, 0, 0);                           \
            }                                                                  \
        }
        PVU(0)
        PVU(1)
        PVU(2)
        PVU(3)
#undef PVU
        __builtin_amdgcn_s_setprio(0);

        __syncthreads();   // before next tile restages sK/sV
    }

    float linv[4];
#pragma unroll
    for (int r = 0; r < 4; r++)
        linv[r] = 1.f / __shfl(l_q, g*4 + r);
#pragma unroll
    for (int d = 0; d < 4; d++)
#pragma unroll
        for (int r = 0; r < 4; r++)
            CTX[((size_t)(b*SS) + q0 + w*16 + g*4 + r)*HH + h*64 + d*16 + l16]
                = f2bs(O[d][r] * linv[r]);
}

// ---------------------------------------------------------------------------
// Out(bf16) = LayerNorm(P0 + P1 + bias + R) * g + beta; optional fp32 OutF.
// P = two f32 split-K partials [2][MTOK][HH]; R = bf16 residual.
// One WAVE per row, shfl-only reductions.
// ---------------------------------------------------------------------------
__global__ __launch_bounds__(256)
void add_ln3(const float* __restrict__ P, const float* __restrict__ bvec,
             const short* __restrict__ R,
             const float* __restrict__ g, const float* __restrict__ beta,
             short* __restrict__ Out, float* __restrict__ OutF)
{
    const int lane = threadIdx.x & 63;
    const int row  = blockIdx.x * 4 + (threadIdx.x >> 6);
    const size_t base = (size_t)row * HH;
    const size_t sH = (size_t)MTOK * HH;

    float v[12];
    float s = 0.f;
#pragma unroll
    for (int p = 0; p < 3; p++) {
        const int c = p*256 + lane*4;
        float4 p0 = *(const float4*)&P[base + c];
        float4 p1 = *(const float4*)&P[sH + base + c];
        float4 bv4 = *(const float4*)&bvec[c];
        bf16x4 rv = *(const bf16x4*)&R[base + c];
        float x0 = p0.x + p1.x + bv4.x + bs2f(rv[0]);
        float x1 = p0.y + p1.y + bv4.y + bs2f(rv[1]);
        float x2 = p0.z + p1.z + bv4.z + bs2f(rv[2]);
        float x3 = p0.w + p1.w + bv4.w + bs2f(rv[3]);
        v[p*4+0] = x0; v[p*4+1] = x1; v[p*4+2] = x2; v[p*4+3] = x3;
        s += (x0 + x1) + (x2 + x3);
    }
    s += __shfl_xor(s, 1);  s += __shfl_xor(s, 2);  s += __shfl_xor(s, 4);
    s += __shfl_xor(s, 8);  s += __shfl_xor(s, 16); s += __shfl_xor(s, 32);
    const float mu = s * (1.f / HH);

    float s2 = 0.f;
#pragma unroll
    for (int j = 0; j < 12; j++) { float d = v[j] - mu; s2 += d * d; }
    s2 += __shfl_xor(s2, 1);  s2 += __shfl_xor(s2, 2);  s2 += __shfl_xor(s2, 4);
    s2 += __shfl_xor(s2, 8);  s2 += __shfl_xor(s2, 16); s2 += __shfl_xor(s2, 32);
    const float rstd = rsqrtf(s2 * (1.f / HH) + 1e-12f);

#pragma unroll
    for (int p = 0; p < 3; p++) {
        const int c = p*256 + lane*4;
        float4 gv = *(const float4*)&g[c];
        float4 bv = *(const float4*)&beta[c];
        float o0 = (v[p*4+0] - mu) * rstd * gv.x + bv.x;
        float o1 = (v[p*4+1] - mu) * rstd * gv.y + bv.y;
        float o2 = (v[p*4+2] - mu) * rstd * gv.z + bv.z;
        float o3 = (v[p*4+3] - mu) * rstd * gv.w + bv.w;
        bf16x4 ov; ov[0] = f2bs(o0); ov[1] = f2bs(o1); ov[2] = f2bs(o2); ov[3] = f2bs(o3);
        *(bf16x4*)&Out[base + c] = ov;
        if (OutF) {
            float4 of; of.x = o0; of.y = o1; of.z = o2; of.w = o3;
            *(float4*)&OutF[base + c] = of;
        }
    }
}

// ---------------------------------------------------------------------------
extern "C" void kernel_launch(void* const* d_in, const int* in_sizes, int n_in,
                              void* d_out, int out_size, void* d_ws, size_t ws_size,
                              hipStream_t stream)
{
    const float* hs    = (const float*)d_in[0];
    const float* mask  = (const float*)d_in[1];
    const float* biasM = (const float*)d_in[2];
    const float* coef  = (const float*)d_in[3];
    const float* Wq    = (const float*)d_in[4];
    const float* bq    = (const float*)d_in[5];
    const float* Wk    = (const float*)d_in[6];
    const float* bk    = (const float*)d_in[7];
    const float* Wv    = (const float*)d_in[8];
    const float* bv    = (const float*)d_in[9];
    const float* Wo    = (const float*)d_in[10];
    const float* bo    = (const float*)d_in[11];
    const float* ln1g  = (const float*)d_in[12];
    const float* ln1b  = (const float*)d_in[13];
    const float* Wi    = (const float*)d_in[14];
    const float* bi    = (const float*)d_in[15];
    const float* Wo2   = (const float*)d_in[16];
    const float* bo2   = (const float*)d_in[17];
    const float* ln2g  = (const float*)d_in[18];
    const float* ln2b  = (const float*)d_in[19];

    // ---- workspace (~108 MB; 138 MB proven available) ----
    const size_t sH   = (size_t)MTOK * HH;
    const size_t sQK  = (size_t)MTOK * 1536;
    const size_t sVt  = (size_t)HH * MTOK;
    const size_t WPL  = 7077888;
    short* wt    = (short*)d_ws;
    float* bqkv  = (float*)(wt + 2*WPL);
    short* bFrag = (short*)(bqkv + 2*2304);       // [2*SS*SS] bias+mask C-frags
    short* X     = bFrag + (size_t)2*SS*SS;
    short* X2    = X  + sH;
    short* QK    = X2 + sH;
    short* Vt    = QK + sQK;
    short* CTX   = Vt + sVt;
    float* PK    = (float*)(CTX + sH);            // [2][MTOK][HH] f32 partials
    short* INTER = QK;

    const dim3 blk(256);

    // ---- prep: batched transposes, bias frags, bias pack, hs cvt ----
    TJobs jH, jI, jO;
    for (int l = 0; l < NLAYER; l++) {
        short* wl = wt + (size_t)l * WPL;
        jH.src[l*4+0] = Wq + (size_t)l*HH*HH;  jH.dst[l*4+0] = wl;
        jH.src[l*4+1] = Wk + (size_t)l*HH*HH;  jH.dst[l*4+1] = wl + 768*768;
        jH.src[l*4+2] = Wv + (size_t)l*HH*HH;  jH.dst[l*4+2] = wl + 1536*768;
        jH.src[l*4+3] = Wo + (size_t)l*HH*HH;  jH.dst[l*4+3] = wl + 1769472;
        jI.src[l] = Wi  + (size_t)l*HH*FFD;    jI.dst[l] = wl + 2359296;
        jO.src[l] = Wo2 + (size_t)l*FFD*HH;    jO.dst[l] = wl + 4718592;
    }
    transpose_cvt_batch<<<dim3(24,24,8), blk, 0, stream>>>(jH, HH, HH);
    transpose_cvt_batch<<<dim3(24,96,2), blk, 0, stream>>>(jI, HH, FFD);
    transpose_cvt_batch<<<dim3(96,24,2), blk, 0, stream>>>(jO, FFD, HH);
    bias_frag_prep<<<dim3(SS/64, SS/128), blk, 0, stream>>>(biasM, mask, coef, bFrag);
    pack_bias<<<dim3((NLAYER*2304 + 255)/256), blk, 0, stream>>>(bq, bk, bv, bqkv);
    cvt_bf16<<<dim3((int)((sH + 255)/256)), blk, 0, stream>>>(hs, X, (int)sH);

    const dim3 gQKV(2304/128, MTOK/128);      // [18, 32] = 576
    const dim3 gSK (HH/64,    MTOK/128, 2);   // [12, 32, 2] split-K (384/plane)
    const dim3 gFF (FFD/128,  MTOK/128);      // [24, 32] = 768
    const dim3 gA  (SS/64, NHEAD, BB);        // [32, 12, 2] = 768 blocks
    const dim3 gLN (MTOK/4);                  // wave-per-row LN
    const int NOSPLIT = 1 << 30;

    for (int l = 0; l < NLAYER; l++) {
        short* wl = wt + (size_t)l * WPL;
        gemm_mfma<<<gQKV, blk, 0, stream>>>(X, wl, bqkv + l*2304, QK, 1536,
                                            MTOK, 2304, HH, 0, Vt, 1536,
                                            QSCALE, 768);
        attn_fused<<<gA, blk, 0, stream>>>(QK, Vt, bFrag, CTX);
        gemm_n64_splitk<<<gSK, blk, 0, stream>>>(CTX, wl + 1769472, PK, HH);
        add_ln3<<<gLN, blk, 0, stream>>>(PK, bo + l*HH, X, ln1g + l*HH, ln1b + l*HH,
                                         X2, nullptr);
        gemm_mfma<<<gFF, blk, 0, stream>>>(X2, wl + 2359296, bi + l*FFD, INTER, FFD,
                                           MTOK, FFD, HH, 1, nullptr, NOSPLIT,
                                           1.f, 0);
        gemm_n64_splitk<<<gSK, blk, 0, stream>>>(INTER, wl + 4718592, PK, FFD);
        add_ln3<<<gLN, blk, 0, stream>>>(PK, bo2 + l*HH, X2, ln2g + l*HH, ln2b + l*HH,
                                         X, (l == NLAYER-1) ? (float*)d_out : nullptr);
    }
}